// Round 15
// baseline (166.327 us; speedup 1.0000x reference)
//
#include <hip/hip_runtime.h>
#include <hip/hip_bf16.h>
#include <math.h>

typedef __attribute__((ext_vector_type(8))) short bf16x8;
typedef __attribute__((ext_vector_type(16))) float f32x16;

namespace {
constexpr int kB = 2, kS = 2048, kE = 1024, kNH = 8, kDH = 128, kE3 = 3072;
constexpr float kLog2e = 1.4426950408889634f;
constexpr int kUnits = 27;        // work units per bh (chunks of <=14 kv-steps)
constexpr int kSplitPerBh = 20;   // partial chunks per bh
}

// units sorted by descending step count (heavy first)
__device__ const int kOrder[kUnits] = {6,19,20,17,18,5,15,16,13,14,24,25,4,
                                       11,12,21,22,23,26,9,10,3,7,8,2,1,0};

__device__ __forceinline__ ushort f2bf(float x) {
  union { __hip_bfloat16 b; ushort u; } c; c.b = __float2bfloat16(x); return c.u;
}
__device__ __forceinline__ uint pk2(float a, float b) {
  return (uint)f2bf(a) | ((uint)f2bf(b) << 16);
}
__device__ __forceinline__ void gload16(const void* g, void* l) {
  __builtin_amdgcn_global_load_lds(
      (const __attribute__((address_space(1))) void*)g,
      (__attribute__((address_space(3))) void*)l, 16, 0, 0);
}
__device__ __forceinline__ f32x16 zero16() {
  f32x16 z;
#pragma unroll
  for (int i = 0; i < 16; ++i) z[i] = 0.f;
  return z;
}
union UB8 { uint4 u; bf16x8 f; };

// ---------------- prep: convkv (blocks 0-255, 128-token tiles) + gates (blocks 256-1279) ----------------
__global__ __launch_bounds__(256, 4) void prep_kernel(
    const float* __restrict__ q, const float* __restrict__ k, const float* __restrict__ v,
    const float* __restrict__ iw, const float* __restrict__ ib,
    const float* __restrict__ fw, const float* __restrict__ fb,
    ushort* __restrict__ Kb, ushort* __restrict__ Vtb,
    float* __restrict__ gtmp) {
  const int bid = blockIdx.x;
  const int tid = threadIdx.x;
  __shared__ ushort Vst[128 * 128];  // 32 KB (convkv path), rows of 256B, 16-chunk XOR swizzle
  __shared__ float red[4][32];       // gates path

  if (bid < 256) {
    // ---- convkv: bh = bid>>4, 128-token s-tile = bid&15 ----
    const int bh = bid >> 4;
    const int b = bh >> 3, h = bh & 7;
    const int s0 = (bid & 15) * 128;
    // phase 1: convert K -> Kb (full-line writes), stage V -> LDS
#pragma unroll
    for (int iter = 0; iter < 4; ++iter) {
      const int tl = iter * 32 + (tid >> 3);
      const int d0 = (tid & 7) * 16;
      const int s = s0 + tl;
      const size_t base = ((size_t)b * kS + s) * kE + h * kDH + d0;
      const float4 k0 = *reinterpret_cast<const float4*>(k + base);
      const float4 k1 = *reinterpret_cast<const float4*>(k + base + 4);
      const float4 k2 = *reinterpret_cast<const float4*>(k + base + 8);
      const float4 k3 = *reinterpret_cast<const float4*>(k + base + 12);
      uint4 pa, pb;
      pa.x = pk2(k0.x, k0.y); pa.y = pk2(k0.z, k0.w);
      pa.z = pk2(k1.x, k1.y); pa.w = pk2(k1.z, k1.w);
      pb.x = pk2(k2.x, k2.y); pb.y = pk2(k2.z, k2.w);
      pb.z = pk2(k3.x, k3.y); pb.w = pk2(k3.z, k3.w);
      ushort* kd = Kb + ((size_t)bh * kS + s) * 128 + d0;
      *reinterpret_cast<uint4*>(kd) = pa;
      *reinterpret_cast<uint4*>(kd + 8) = pb;

      const float4 v0 = *reinterpret_cast<const float4*>(v + base);
      const float4 v1 = *reinterpret_cast<const float4*>(v + base + 4);
      const float4 v2 = *reinterpret_cast<const float4*>(v + base + 8);
      const float4 v3 = *reinterpret_cast<const float4*>(v + base + 12);
      uint4 va, vb4;
      va.x = pk2(v0.x, v0.y); va.y = pk2(v0.z, v0.w);
      va.z = pk2(v1.x, v1.y); va.w = pk2(v1.z, v1.w);
      vb4.x = pk2(v2.x, v2.y); vb4.y = pk2(v2.z, v2.w);
      vb4.z = pk2(v3.x, v3.y); vb4.w = pk2(v3.z, v3.w);
      const int c0 = d0 >> 3;
      char* row = reinterpret_cast<char*>(Vst) + tl * 256;
      *reinterpret_cast<uint4*>(row + (((c0 + 0) ^ (tl & 15)) << 4)) = va;
      *reinterpret_cast<uint4*>(row + (((c0 + 1) ^ (tl & 15)) << 4)) = vb4;
    }
    __syncthreads();
    // phase 2: d = tid>>1, half = tid&1 -> 64 tokens -> 128B contiguous write
    {
      const int d = tid >> 1, half = tid & 1;
      const int cd = d >> 3;
      const int od = (d & 7) * 2;
      uint tmp[32];
#pragma unroll
      for (int p = 0; p < 32; ++p) {
        const int t = half * 64 + 2 * p;
        const ushort u0 = *reinterpret_cast<const ushort*>(
            reinterpret_cast<const char*>(Vst) + t * 256 + ((cd ^ (t & 15)) << 4) + od);
        const ushort u1 = *reinterpret_cast<const ushort*>(
            reinterpret_cast<const char*>(Vst) + (t + 1) * 256 + ((cd ^ ((t + 1) & 15)) << 4) + od);
        tmp[p] = (uint)u0 | ((uint)u1 << 16);
      }
      ushort* vd = Vtb + ((size_t)bh * kDH + d) * kS + s0 + half * 64;
#pragma unroll
      for (int p = 0; p < 8; ++p)
        *reinterpret_cast<uint4*>(vd + p * 8) = *reinterpret_cast<const uint4*>(&tmp[p * 4]);
    }
  } else {
    // ---- gates: 4 tokens/block in 2 passes of 2 tokens; bit-identical to R13 tree ----
    const int w = tid >> 6, lane = tid & 63;
    const int tokbase = (bid - 256) * 4;
    for (int pp = 0; pp < 2; ++pp) {
      float acc[32];  // acc[t2*16 + g], g: 0-7 i, 8-15 f
#pragma unroll
      for (int i = 0; i < 32; ++i) acc[i] = 0.f;

      for (int step = 0; step < 12; ++step) {
        const int e = w * 768 + step * 64 + lane;
        const int seg = e >> 10;
        const int eo = e & 1023;
        const float* __restrict__ src = (seg == 0) ? q : (seg == 1) ? k : v;
        float gv[2];
#pragma unroll
        for (int t2 = 0; t2 < 2; ++t2)
          gv[t2] = src[(size_t)(tokbase + pp * 2 + t2) * kE + eo];
        float wi[8], wf[8];
#pragma unroll
        for (int hh = 0; hh < 8; ++hh) {
          wi[hh] = iw[hh * kE3 + e];
          wf[hh] = fw[hh * kE3 + e];
        }
#pragma unroll
        for (int t2 = 0; t2 < 2; ++t2) {
#pragma unroll
          for (int hh = 0; hh < 8; ++hh) {
            acc[t2 * 16 + hh]     += gv[t2] * wi[hh];
            acc[t2 * 16 + 8 + hh] += gv[t2] * wf[hh];
          }
        }
      }
      // 5-level compaction butterfly (lane bits 1,2,4,8,16), then bit 32:
      // reproduces R13's 6-level lane-pair order exactly.
      int cur = 32;
#pragma unroll
      for (int lv = 0; lv < 5; ++lv) {
        const int bmask = 1 << lv;
        const int half = cur >> 1;
        const bool hib = (lane & bmask) != 0;
#pragma unroll
        for (int i = 0; i < 16; ++i) {
          if (i >= half) break;
          const float keep = hib ? acc[i + half] : acc[i];
          const float send = hib ? acc[i] : acc[i + half];
          acc[i] = keep + __shfl_xor(send, bmask);
        }
        cur = half;
      }
      const float tot = acc[0] + __shfl_xor(acc[0], 32);
      const int l5 = lane & 31;
      const int a = ((l5 & 1) << 4) | ((l5 & 2) << 2) | (l5 & 4) |
                    ((l5 & 8) >> 2) | ((l5 & 16) >> 4);
      if (lane < 32) red[w][a] = tot;
      __syncthreads();
      if (tid < 32) {
        const float val = red[0][tid] + red[1][tid] + red[2][tid] + red[3][tid];
        const int t2 = tid >> 4, gate = tid & 15, hh = gate & 7;
        gtmp[(size_t)(tokbase + pp * 2 + t2) * 16 + gate] =
            val + (gate < 8 ? ib[hh] : fb[hh]);
      }
      __syncthreads();   // red reused next pass
    }
  }
}

// ---------------- scan: wt (f32, exact), M2 (log2), nfl, per-64-tile max Cg ----------------
__global__ __launch_bounds__(256) void scan_kernel(
    const float* __restrict__ gtmp,
    float* __restrict__ wt_out, float* __restrict__ M2_out, float* __restrict__ nfl_out,
    float* __restrict__ Cg) {
  const int bh = blockIdx.x;
  const int b = bh >> 3, h = bh & 7;
  const int tid = threadIdx.x;
  const int w = tid >> 6, lane = tid & 63;
  __shared__ float wsum[4], wmax[4];
  const float* __restrict__ gt = gtmp + (size_t)b * kS * 16;
  const int s0 = tid * 8;

  float lf[8];
#pragma unroll
  for (int j = 0; j < 8; ++j) {
    const float f = gt[(size_t)(s0 + j) * 16 + 8 + h];
    lf[j] = fminf(f, 0.f) - log1pf(expf(-fabsf(f)));
  }
  float run = 0.f, pcs[8];
#pragma unroll
  for (int j = 0; j < 8; ++j) { run += lf[j]; pcs[j] = run; }
  float x = run;
#pragma unroll
  for (int d = 1; d < 64; d <<= 1) {
    const float t = __shfl_up(x, d);
    if (lane >= d) x += t;
  }
  if (lane == 63) wsum[w] = x;
  __syncthreads();
  float woff = 0.f;
#pragma unroll
  for (int i = 0; i < 4; ++i) if (i < w) woff += wsum[i];
  const float csbase = woff + x - run;
  float cs[8];
#pragma unroll
  for (int j = 0; j < 8; ++j) cs[j] = csbase + pcs[j];

  float av[8];
#pragma unroll
  for (int j = 0; j < 8; ++j)
    av[j] = gt[(size_t)(s0 + j) * 16 + h] - cs[j];
  float rmax = -1e30f, pm[8];
#pragma unroll
  for (int j = 0; j < 8; ++j) { rmax = fmaxf(rmax, av[j]); pm[j] = rmax; }

  float tm = rmax;
  tm = fmaxf(tm, __shfl_xor(tm, 1));
  tm = fmaxf(tm, __shfl_xor(tm, 2));
  tm = fmaxf(tm, __shfl_xor(tm, 4));
  if ((lane & 7) == 0) Cg[bh * 32 + (tid >> 3)] = tm * kLog2e;

  float4 wtlo, wthi;
  wtlo.x = exp2f((av[0] - tm) * kLog2e); wtlo.y = exp2f((av[1] - tm) * kLog2e);
  wtlo.z = exp2f((av[2] - tm) * kLog2e); wtlo.w = exp2f((av[3] - tm) * kLog2e);
  wthi.x = exp2f((av[4] - tm) * kLog2e); wthi.y = exp2f((av[5] - tm) * kLog2e);
  wthi.z = exp2f((av[6] - tm) * kLog2e); wthi.w = exp2f((av[7] - tm) * kLog2e);

  float mi = rmax;
#pragma unroll
  for (int d = 1; d < 64; d <<= 1) {
    const float t = __shfl_up(mi, d);
    if (lane >= d) mi = fmaxf(mi, t);
  }
  if (lane == 63) wmax[w] = mi;
  float mexcl = __shfl_up(mi, 1);
  if (lane == 0) mexcl = -1e30f;
  __syncthreads();
  float wmoff = -1e30f;
#pragma unroll
  for (int i = 0; i < 4; ++i) if (i < w) wmoff = fmaxf(wmoff, wmax[i]);
  const float mbase = fmaxf(wmoff, mexcl);

  float M[8];
#pragma unroll
  for (int j = 0; j < 8; ++j) M[j] = fmaxf(mbase, pm[j]);
  float4 m2lo, m2hi, nflo, nfhi;
  m2lo.x = M[0] * kLog2e; m2lo.y = M[1] * kLog2e; m2lo.z = M[2] * kLog2e; m2lo.w = M[3] * kLog2e;
  m2hi.x = M[4] * kLog2e; m2hi.y = M[5] * kLog2e; m2hi.z = M[6] * kLog2e; m2hi.w = M[7] * kLog2e;
  nflo.x = expf(-(cs[0] + M[0])); nflo.y = expf(-(cs[1] + M[1]));
  nflo.z = expf(-(cs[2] + M[2])); nflo.w = expf(-(cs[3] + M[3]));
  nfhi.x = expf(-(cs[4] + M[4])); nfhi.y = expf(-(cs[5] + M[5]));
  nfhi.z = expf(-(cs[6] + M[6])); nfhi.w = expf(-(cs[7] + M[7]));
  const size_t o = (size_t)bh * kS + s0;
  *reinterpret_cast<float4*>(wt_out + o) = wtlo;
  *reinterpret_cast<float4*>(wt_out + o + 4) = wthi;
  *reinterpret_cast<float4*>(M2_out + o) = m2lo;
  *reinterpret_cast<float4*>(M2_out + o + 4) = m2hi;
  *reinterpret_cast<float4*>(nfl_out + o) = nflo;
  *reinterpret_cast<float4*>(nfl_out + o + 4) = nfhi;
}

// ---------------- attn: 4 waves, 32x32 MFMA, single-buffer LDS (33 KB -> 4 blocks/CU) ----------------
__global__ __launch_bounds__(256, 2) void attn_mfma_kernel(
    const float* __restrict__ qg, const ushort* __restrict__ Kb,
    const ushort* __restrict__ Vtb, const float* __restrict__ wt,
    const float* __restrict__ Cg, const float* __restrict__ M2,
    const float* __restrict__ nfl, const float* __restrict__ nw,
    float* __restrict__ out, float* __restrict__ ph, float* __restrict__ prs) {
  // XCD-capacity swizzle: each XCD sees only 2 bh -> K/V fits 4MB L2
  const int id = blockIdx.x;
  const int r8 = id & 7, qq = id >> 3;
  const int bh = r8 + 8 * (qq & 1);
  const int u = kOrder[qq >> 1];
  const int b = bh >> 3, h = bh & 7;
  int it, j0, j1, cid = -1;
  if (u <= 6) { it = u; const int T = 2 * it + 2; j0 = 0; j1 = T - 1; }
  else if (u <= 20) {
    const int s = u - 7; it = 7 + (s >> 1); const int ci = s & 1;
    const int T = 2 * it + 2;
    j0 = (T * ci) >> 1; j1 = ((T * (ci + 1)) >> 1) - 1;
    cid = bh * kSplitPerBh + (u - 7);
  } else {
    const int s = u - 21; it = 14 + (s >= 3 ? 1 : 0); const int ci = s - (s >= 3 ? 3 : 0);
    const int T = 2 * it + 2;
    j0 = (T * ci) / 3; j1 = (T * (ci + 1)) / 3 - 1;
    cid = bh * kSplitPerBh + (u - 7);
  }
  const int tid = threadIdx.x;
  const int w = tid >> 6, lane = tid & 63;
  const int l31 = lane & 31, hi = lane >> 5;
  const int row_w = it * 128 + w * 32;
  const int ig = row_w + l31;
  const size_t bhS = (size_t)bh * kS;

  __shared__ ushort Klds[64 * 128];   // 16 KB, single buffer
  __shared__ ushort Vlds[128 * 64];   // 16 KB
  __shared__ float Wtl[64];           // 256 B decay weights

  const char* __restrict__ KgBase = reinterpret_cast<const char*>(Kb + bhS * 128);
  const char* __restrict__ VgBase = reinterpret_cast<const char*>(Vtb + (size_t)bh * 128 * kS);
  const char* __restrict__ WgBase = reinterpret_cast<const char*>(wt + bhS);

  // Q fragments: B[k=d][col=i]
  bf16x8 qf[8];
  {
    const float scale = 0.08838834764831845f;
    const float* qrow = qg + ((size_t)b * kS + ig) * kE + h * kDH;
#pragma unroll
    for (int ks = 0; ks < 8; ++ks) {
      const int d0 = ks * 16 + hi * 8;
      const float4 lo = *reinterpret_cast<const float4*>(qrow + d0);
      const float4 hi4 = *reinterpret_cast<const float4*>(qrow + d0 + 4);
      UB8 f;
      f.u.x = pk2(lo.x * scale, lo.y * scale);
      f.u.y = pk2(lo.z * scale, lo.w * scale);
      f.u.z = pk2(hi4.x * scale, hi4.y * scale);
      f.u.w = pk2(hi4.z * scale, hi4.w * scale);
      qf[ks] = f.f;
    }
  }
  const float M2i = M2[bhS + ig];
  const float cgreg = Cg[bh * 32 + l31];     // all 32 tile maxima in regs

  int koffG[4], voffG[4];
#pragma unroll
  for (int i = 0; i < 4; ++i) {
    const int L = tid * 16 + i * 4096;
    { const int j = L >> 8, c = (L >> 4) & 15;
      koffG[i] = j * 256 + ((c ^ (j & 15)) << 4); }
    { const int d = L >> 7, c = (L >> 4) & 7;
      voffG[i] = d * 4096 + ((c ^ (d & 7)) << 4); }
  }
  auto stage = [&](int jt) {
    const char* Kg = KgBase + (size_t)jt * 16384;
    const char* Vg = VgBase + (size_t)jt * 128;
    char* kl = reinterpret_cast<char*>(Klds) + tid * 16;
    char* vl = reinterpret_cast<char*>(Vlds) + tid * 16;
#pragma unroll
    for (int i = 0; i < 4; ++i) gload16(Kg + koffG[i], kl + i * 4096);
#pragma unroll
    for (int i = 0; i < 4; ++i) gload16(Vg + voffG[i], vl + i * 4096);
    if (tid < 16)
      gload16(WgBase + jt * 256 + tid * 16,
              reinterpret_cast<char*>(Wtl) + tid * 16);
  };

  f32x16 hacc[4];
#pragma unroll
  for (int dc = 0; dc < 4; ++dc) hacc[dc] = zero16();
  float rs = 0.f;

  for (int jt = j0; jt <= j1; ++jt) {
    __syncthreads();            // all waves done reading previous tile
    stage(jt);
    __syncthreads();            // staging loads landed (vmcnt drained at barrier)

    const int jlo = jt * 64;
    const bool v0 = (jlo <= row_w + 31);
    const bool v1 = (jlo + 32 <= row_w + 31);
    const bool fullmask = (jlo + 63 <= row_w);
    if (!v0) continue;

    const float f = exp2f(__shfl(cgreg, jt) - M2i);   // no memory access
    const char* kb = reinterpret_cast<const char*>(Klds);
    const char* vb = reinterpret_cast<const char*>(Vlds);
    const int ksw = (l31 & 15) << 4;

    // ---- swapped QK: S^T[j][i] ----
    f32x16 sacc0 = zero16(), sacc1 = zero16();
#pragma unroll
    for (int ks = 0; ks < 8; ++ks) {
      const int colb = 32 * ks + 16 * hi;
      const bf16x8 kf0 = *reinterpret_cast<const bf16x8*>(
          kb + l31 * 256 + (colb ^ ksw));
      sacc0 = __builtin_amdgcn_mfma_f32_32x32x16_bf16(kf0, qf[ks], sacc0, 0, 0, 0);
      if (v1) {
        const bf16x8 kf1 = *reinterpret_cast<const bf16x8*>(
            kb + (32 + l31) * 256 + (colb ^ ksw));
        sacc1 = __builtin_amdgcn_mfma_f32_32x32x16_bf16(kf1, qf[ks], sacc1, 0, 0, 0);
      }
    }

    // ---- P = S' * wt[j] * f (wt via broadcast b128 from LDS; mask on diagonal) ----
    uint pkw[2][8];
#pragma unroll
    for (int jc = 0; jc < 2; ++jc) {
      if (jc == 1 && !v1) break;
      const f32x16 sa = jc ? sacc1 : sacc0;
      float p[16];
#pragma unroll
      for (int q2 = 0; q2 < 4; ++q2) {
        const float4 wq = *reinterpret_cast<const float4*>(
            &Wtl[jc * 32 + q2 * 8 + 4 * hi]);
        const float wv[4] = {wq.x, wq.y, wq.z, wq.w};
#pragma unroll
        for (int m = 0; m < 4; ++m) {
          const int r = q2 * 4 + m;
          const int c = m + 8 * q2;
          float val = sa[r] * (wv[m] * f);
          if (!fullmask) val = (jlo + jc * 32 + c + 4 * hi <= ig) ? val : 0.f;
          rs += val; p[r] = val;
        }
      }
#pragma unroll
      for (int q2 = 0; q2 < 8; ++q2) pkw[jc][q2] = pk2(p[2 * q2], p[2 * q2 + 1]);
    }

    // ---- PV: H[i][d] ----
#pragma unroll
    for (int ks = 0; ks < 4; ++ks) {
      const int jc = ks >> 1, ks2 = ks & 1;
      if (jc == 1 && !v1) break;
      UB8 pf;
      pf.u.x = pkw[jc][ks2 * 4 + 0]; pf.u.y = pkw[jc][ks2 * 4 + 1];
      pf.u.z = pkw[jc][ks2 * 4 + 2]; pf.u.w = pkw[jc][ks2 * 4 + 3];
      const int colb = 64 * jc + 32 * ks2 + 8 * hi;
#pragma unroll
      for (int dc = 0; dc < 4; ++dc) {
        const int d = dc * 32 + l31;
        const char* vrow = vb + d * 128;
        const int sw = (d & 7) << 4;
        const uint2 a = *reinterpret_cast<const uint2*>(vrow + (colb ^ sw));
        const uint2 c = *reinterpret_cast<const uint2*>(vrow + ((colb + 16) ^ sw));
        UB8 vf; vf.u.x = a.x; vf.u.y = a.y; vf.u.z = c.x; vf.u.w = c.y;
        hacc[dc] = __builtin_amdgcn_mfma_f32_32x32x16_bf16(pf.f, vf.f, hacc[dc], 0, 0, 0);
      }
    }
  }

  const float rs_tot = rs + __shfl_xor(rs, 32);

  if (cid >= 0) {
    float* pb = ph + (size_t)cid * 16384;
#pragma unroll
    for (int dc = 0; dc < 4; ++dc)
#pragma unroll
      for (int r = 0; r < 16; ++r) {
        const int il = w * 32 + (r & 3) + 8 * (r >> 2) + 4 * hi;
        pb[il * 128 + dc * 32 + l31] = hacc[dc][r];
      }
    if (hi == 0) prs[cid * 128 + w * 32 + l31] = rs_tot;
    return;
  }

  // ---- inline epilogue (rowsum via shfl; no LDS) ----
  float nwv[4];
#pragma unroll
  for (int dc = 0; dc < 4; ++dc) nwv[dc] = nw[h * kDH + dc * 32 + l31];
#pragma unroll
  for (int r = 0; r < 16; ++r) {
    const int imap = (r & 3) + 8 * (r >> 2) + 4 * hi;
    const float rsum = __shfl(rs_tot, imap);
    const float nf = nfl[bhS + row_w + imap];
    const float inv = 1.f / (fmaxf(fabsf(rsum), nf) + 1e-6f);
    float hv[4];
    float s1 = 0.f, s2 = 0.f;
#pragma unroll
    for (int dc = 0; dc < 4; ++dc) {
      hv[dc] = hacc[dc][r] * inv;
      s1 += hv[dc]; s2 += hv[dc] * hv[dc];
    }
#pragma unroll
    for (int off = 1; off <= 16; off <<= 1) {
      s1 += __shfl_xor(s1, off);
      s2 += __shfl_xor(s2, off);
    }
    const float mu = s1 * (1.f / 128.f);
    const float var = s2 * (1.f / 128.f) - mu * mu;
    const float rstd = rsqrtf(var + 1e-5f);
    float* __restrict__ orow = out + ((size_t)b * kS + row_w + imap) * kE + h * kDH;
#pragma unroll
    for (int dc = 0; dc < 4; ++dc)
      orow[dc * 32 + l31] = (hv[dc] - mu) * rstd * nwv[dc];
  }
}

// ---------------- combine: sum chunk partials, normalize, groupnorm, store ----------------
__global__ __launch_bounds__(256) void combine_kernel(
    const float* __restrict__ ph, const float* __restrict__ prs,
    const float* __restrict__ nfl, const float* __restrict__ nw,
    float* __restrict__ out) {
  const int blk = blockIdx.x;
  const int bh = blk / 9, ct = blk % 9;
  const int b = bh >> 3, h = bh & 7;
  const int it = 7 + ct;
  const int nc = (ct < 7) ? 2 : 3;
  const int cb0 = bh * kSplitPerBh + ((ct < 7) ? ct * 2 : 14 + (ct - 7) * 3);
  const int tid = threadIdx.x;
  __shared__ float sinv[128];
  if (tid < 128) {
    float rsum = 0.f;
    for (int c = 0; c < nc; ++c) rsum += prs[(cb0 + c) * 128 + tid];
    const float nf = nfl[(size_t)bh * kS + it * 128 + tid];
    sinv[tid] = 1.f / (fmaxf(fabsf(rsum), nf) + 1e-6f);
  }
  __syncthreads();
  for (int kk = 0; kk < 16; ++kk) {
    const int idx = kk * 256 + tid;
    const int row = idx >> 5, c4 = idx & 31;
    float ax = 0.f, ay = 0.f, az = 0.f, aw = 0.f;
    for (int c = 0; c < nc; ++c) {
      const float4 t = *reinterpret_cast<const float4*>(
          ph + (size_t)(cb0 + c) * 16384 + row * 128 + c4 * 4);
      ax += t.x; ay += t.y; az += t.z; aw += t.w;
    }
    const float inv = sinv[row];
    ax *= inv; ay *= inv; az *= inv; aw *= inv;
    float s1 = ax + ay + az + aw;
    float s2 = ax * ax + ay * ay + az * az + aw * aw;
#pragma unroll
    for (int off = 1; off <= 16; off <<= 1) {
      s1 += __shfl_xor(s1, off);
      s2 += __shfl_xor(s2, off);
    }
    const float mu = s1 * (1.f / 128.f);
    const float var = s2 * (1.f / 128.f) - mu * mu;
    const float rstd = rsqrtf(var + 1e-5f);
    const float4 nw4 = *reinterpret_cast<const float4*>(nw + h * kDH + c4 * 4);
    float4 o;
    o.x = (ax - mu) * rstd * nw4.x;
    o.y = (ay - mu) * rstd * nw4.y;
    o.z = (az - mu) * rstd * nw4.z;
    o.w = (aw - mu) * rstd * nw4.w;
    *reinterpret_cast<float4*>(
        out + ((size_t)b * kS + it * 128 + row) * kE + h * kDH + c4 * 4) = o;
  }
}

extern "C" void kernel_launch(void* const* d_in, const int* in_sizes, int n_in,
                              void* d_out, int out_size, void* d_ws, size_t ws_size,
                              hipStream_t stream) {
  const float* q  = (const float*)d_in[0];
  const float* k  = (const float*)d_in[1];
  const float* v  = (const float*)d_in[2];
  const float* iw = (const float*)d_in[3];
  const float* ib = (const float*)d_in[4];
  const float* fw = (const float*)d_in[5];
  const float* fb = (const float*)d_in[6];
  const float* nw = (const float*)d_in[7];
  float* out = (float*)d_out;

  char* ws = (char*)d_ws;
  const int BHS = kB * kNH * kS;                 // 32768
  float* gtmp  = (float*)ws;                     // 4096 tokens x 16 gates = 256 KB
  float* wt    = gtmp + 2 * BHS;
  float* M2    = gtmp + 3 * BHS;
  float* nfl   = gtmp + 4 * BHS;
  float* Cg    = gtmp + 5 * BHS;                 // 512 floats
  ushort* Kb  = (ushort*)(ws + (size_t)(5 * BHS + 512) * 4);
  ushort* Vtb = Kb + (size_t)kB * kNH * kS * kDH;
  float* ph   = (float*)(Vtb + (size_t)kB * kNH * kS * kDH);
  float* prs  = ph + (size_t)320 * 128 * 128;

  prep_kernel<<<dim3(1280), dim3(256), 0, stream>>>(q, k, v, iw, ib, fw, fb,
                                                    Kb, Vtb, gtmp);
  scan_kernel<<<dim3(kB * kNH), dim3(256), 0, stream>>>(gtmp, wt, M2, nfl, Cg);
  attn_mfma_kernel<<<dim3(kUnits * kB * kNH), dim3(256), 0, stream>>>(
      q, Kb, Vtb, wt, Cg, M2, nfl, nw, out, ph, prs);
  combine_kernel<<<dim3(kB * kNH * 9), dim3(256), 0, stream>>>(ph, prs, nfl, nw, out);
}

// Round 16
// 100.497 us; speedup vs baseline: 1.6550x; 1.6550x over previous
//
#include <hip/hip_runtime.h>
#include <hip/hip_bf16.h>
#include <math.h>

typedef __attribute__((ext_vector_type(8))) short bf16x8;
typedef __attribute__((ext_vector_type(16))) float f32x16;

namespace {
constexpr int kB = 2, kS = 2048, kE = 1024, kNH = 8, kDH = 128, kE3 = 3072;
constexpr float kLog2e = 1.4426950408889634f;
constexpr int kUnits = 27;        // work units per bh (chunks of <=14 kv-steps)
constexpr int kSplitPerBh = 20;   // partial chunks per bh
}

// units sorted by descending step count (heavy first)
__device__ const int kOrder[kUnits] = {6,19,20,17,18,5,15,16,13,14,24,25,4,
                                       11,12,21,22,23,26,9,10,3,7,8,2,1,0};

__device__ __forceinline__ ushort f2bf(float x) {
  union { __hip_bfloat16 b; ushort u; } c; c.b = __float2bfloat16(x); return c.u;
}
__device__ __forceinline__ uint pk2(float a, float b) {
  return (uint)f2bf(a) | ((uint)f2bf(b) << 16);
}
__device__ __forceinline__ void gload16(const void* g, void* l) {
  __builtin_amdgcn_global_load_lds(
      (const __attribute__((address_space(1))) void*)g,
      (__attribute__((address_space(3))) void*)l, 16, 0, 0);
}
__device__ __forceinline__ f32x16 zero16() {
  f32x16 z;
#pragma unroll
  for (int i = 0; i < 16; ++i) z[i] = 0.f;
  return z;
}
union UB8 { uint4 u; bf16x8 f; };

// Compaction butterfly, constant-bound levels (keeps acc[] in REGISTERS — rule #20).
// Pairing order identical to the original break-based version: bit-identical results.
__device__ __forceinline__ float butterfly64(float* acc, int lane) {
#define BF_LEVEL(BMASK, HALF)                                          \
  {                                                                    \
    const bool hib = (lane & (BMASK)) != 0;                            \
    _Pragma("unroll")                                                  \
    for (int i = 0; i < (HALF); ++i) {                                 \
      const float keep = hib ? acc[i + (HALF)] : acc[i];               \
      const float send = hib ? acc[i] : acc[i + (HALF)];               \
      acc[i] = keep + __shfl_xor(send, (BMASK));                       \
    }                                                                  \
  }
  BF_LEVEL(1, 32)
  BF_LEVEL(2, 16)
  BF_LEVEL(4, 8)
  BF_LEVEL(8, 4)
  BF_LEVEL(16, 2)
  BF_LEVEL(32, 1)
#undef BF_LEVEL
  return acc[0];
}

// ---------------- prep: convkv (blocks 0-255, 128-token tiles) + gates (blocks 256-1279) ----------------
__global__ __launch_bounds__(256, 2) void prep_kernel(
    const float* __restrict__ q, const float* __restrict__ k, const float* __restrict__ v,
    const float* __restrict__ iw, const float* __restrict__ ib,
    const float* __restrict__ fw, const float* __restrict__ fb,
    ushort* __restrict__ Kb, ushort* __restrict__ Vtb,
    float* __restrict__ gtmp) {
  const int bid = blockIdx.x;
  const int tid = threadIdx.x;
  __shared__ ushort Vst[128 * 128];  // 32 KB (convkv path), rows of 256B, 16-chunk XOR swizzle
  __shared__ float red[4][64];       // gates path

  if (bid < 256) {
    // ---- convkv: bh = bid>>4, 128-token s-tile = bid&15 ----
    const int bh = bid >> 4;
    const int b = bh >> 3, h = bh & 7;
    const int s0 = (bid & 15) * 128;
    // phase 1: convert K -> Kb (full-line writes), stage V -> LDS
#pragma unroll
    for (int iter = 0; iter < 4; ++iter) {
      const int tl = iter * 32 + (tid >> 3);
      const int d0 = (tid & 7) * 16;
      const int s = s0 + tl;
      const size_t base = ((size_t)b * kS + s) * kE + h * kDH + d0;
      const float4 k0 = *reinterpret_cast<const float4*>(k + base);
      const float4 k1 = *reinterpret_cast<const float4*>(k + base + 4);
      const float4 k2 = *reinterpret_cast<const float4*>(k + base + 8);
      const float4 k3 = *reinterpret_cast<const float4*>(k + base + 12);
      uint4 pa, pb;
      pa.x = pk2(k0.x, k0.y); pa.y = pk2(k0.z, k0.w);
      pa.z = pk2(k1.x, k1.y); pa.w = pk2(k1.z, k1.w);
      pb.x = pk2(k2.x, k2.y); pb.y = pk2(k2.z, k2.w);
      pb.z = pk2(k3.x, k3.y); pb.w = pk2(k3.z, k3.w);
      ushort* kd = Kb + ((size_t)bh * kS + s) * 128 + d0;
      *reinterpret_cast<uint4*>(kd) = pa;
      *reinterpret_cast<uint4*>(kd + 8) = pb;

      const float4 v0 = *reinterpret_cast<const float4*>(v + base);
      const float4 v1 = *reinterpret_cast<const float4*>(v + base + 4);
      const float4 v2 = *reinterpret_cast<const float4*>(v + base + 8);
      const float4 v3 = *reinterpret_cast<const float4*>(v + base + 12);
      uint4 va, vb4;
      va.x = pk2(v0.x, v0.y); va.y = pk2(v0.z, v0.w);
      va.z = pk2(v1.x, v1.y); va.w = pk2(v1.z, v1.w);
      vb4.x = pk2(v2.x, v2.y); vb4.y = pk2(v2.z, v2.w);
      vb4.z = pk2(v3.x, v3.y); vb4.w = pk2(v3.z, v3.w);
      const int c0 = d0 >> 3;
      char* row = reinterpret_cast<char*>(Vst) + tl * 256;
      *reinterpret_cast<uint4*>(row + (((c0 + 0) ^ (tl & 15)) << 4)) = va;
      *reinterpret_cast<uint4*>(row + (((c0 + 1) ^ (tl & 15)) << 4)) = vb4;
    }
    __syncthreads();
    // phase 2: d = tid>>1, half = tid&1 -> 64 tokens -> 128B contiguous write
    {
      const int d = tid >> 1, half = tid & 1;
      const int cd = d >> 3;
      const int od = (d & 7) * 2;
      uint tmp[32];
#pragma unroll
      for (int p = 0; p < 32; ++p) {
        const int t = half * 64 + 2 * p;
        const ushort u0 = *reinterpret_cast<const ushort*>(
            reinterpret_cast<const char*>(Vst) + t * 256 + ((cd ^ (t & 15)) << 4) + od);
        const ushort u1 = *reinterpret_cast<const ushort*>(
            reinterpret_cast<const char*>(Vst) + (t + 1) * 256 + ((cd ^ ((t + 1) & 15)) << 4) + od);
        tmp[p] = (uint)u0 | ((uint)u1 << 16);
      }
      ushort* vd = Vtb + ((size_t)bh * kDH + d) * kS + s0 + half * 64;
#pragma unroll
      for (int p = 0; p < 8; ++p)
        *reinterpret_cast<uint4*>(vd + p * 8) = *reinterpret_cast<const uint4*>(&tmp[p * 4]);
    }
  } else {
    // ---- gates: EXACT R13 math (acc[64], 12 steps, 4-way wave combine); no scratch ----
    const int w = tid >> 6, lane = tid & 63;
    const int tokbase = (bid - 256) * 4;
    float acc[64];  // acc[t*16 + g], g: 0-7 i, 8-15 f
#pragma unroll
    for (int i = 0; i < 64; ++i) acc[i] = 0.f;

    for (int step = 0; step < 12; ++step) {
      const int e = w * 768 + step * 64 + lane;
      const int seg = e >> 10;
      const int eo = e & 1023;
      const float* __restrict__ src = (seg == 0) ? q : (seg == 1) ? k : v;
      float gv[4];
#pragma unroll
      for (int t = 0; t < 4; ++t)
        gv[t] = src[(size_t)(tokbase + t) * kE + eo];
      // weights in groups of 4 (lower live set; per-acc FMA order unchanged)
      float w4[4];
#pragma unroll
      for (int hh = 0; hh < 4; ++hh) w4[hh] = iw[hh * kE3 + e];
#pragma unroll
      for (int t = 0; t < 4; ++t)
#pragma unroll
        for (int hh = 0; hh < 4; ++hh)
          acc[t * 16 + hh] += gv[t] * w4[hh];
#pragma unroll
      for (int hh = 0; hh < 4; ++hh) w4[hh] = iw[(4 + hh) * kE3 + e];
#pragma unroll
      for (int t = 0; t < 4; ++t)
#pragma unroll
        for (int hh = 0; hh < 4; ++hh)
          acc[t * 16 + 4 + hh] += gv[t] * w4[hh];
#pragma unroll
      for (int hh = 0; hh < 4; ++hh) w4[hh] = fw[hh * kE3 + e];
#pragma unroll
      for (int t = 0; t < 4; ++t)
#pragma unroll
        for (int hh = 0; hh < 4; ++hh)
          acc[t * 16 + 8 + hh] += gv[t] * w4[hh];
#pragma unroll
      for (int hh = 0; hh < 4; ++hh) w4[hh] = fw[(4 + hh) * kE3 + e];
#pragma unroll
      for (int t = 0; t < 4; ++t)
#pragma unroll
        for (int hh = 0; hh < 4; ++hh)
          acc[t * 16 + 12 + hh] += gv[t] * w4[hh];
    }
    const float r = butterfly64(acc, lane);
    const int a = ((lane & 1) << 5) | ((lane & 2) << 3) | ((lane & 4) << 1) |
                  ((lane & 8) >> 1) | ((lane & 16) >> 3) | ((lane & 32) >> 5);
    red[w][a] = r;
    __syncthreads();
    if (tid < 64) {
      const float val = red[0][tid] + red[1][tid] + red[2][tid] + red[3][tid];
      const int t = tid >> 4, gate = tid & 15, hh = gate & 7;
      gtmp[(size_t)(tokbase + t) * 16 + gate] =
          val + (gate < 8 ? ib[hh] : fb[hh]);
    }
  }
}

// ---------------- scan: wt (f32, exact), M2 (log2), nfl, per-64-tile max Cg ----------------
__global__ __launch_bounds__(256) void scan_kernel(
    const float* __restrict__ gtmp,
    float* __restrict__ wt_out, float* __restrict__ M2_out, float* __restrict__ nfl_out,
    float* __restrict__ Cg) {
  const int bh = blockIdx.x;
  const int b = bh >> 3, h = bh & 7;
  const int tid = threadIdx.x;
  const int w = tid >> 6, lane = tid & 63;
  __shared__ float wsum[4], wmax[4];
  const float* __restrict__ gt = gtmp + (size_t)b * kS * 16;
  const int s0 = tid * 8;

  float lf[8];
#pragma unroll
  for (int j = 0; j < 8; ++j) {
    const float f = gt[(size_t)(s0 + j) * 16 + 8 + h];
    lf[j] = fminf(f, 0.f) - log1pf(expf(-fabsf(f)));
  }
  float run = 0.f, pcs[8];
#pragma unroll
  for (int j = 0; j < 8; ++j) { run += lf[j]; pcs[j] = run; }
  float x = run;
#pragma unroll
  for (int d = 1; d < 64; d <<= 1) {
    const float t = __shfl_up(x, d);
    if (lane >= d) x += t;
  }
  if (lane == 63) wsum[w] = x;
  __syncthreads();
  float woff = 0.f;
#pragma unroll
  for (int i = 0; i < 4; ++i) if (i < w) woff += wsum[i];
  const float csbase = woff + x - run;
  float cs[8];
#pragma unroll
  for (int j = 0; j < 8; ++j) cs[j] = csbase + pcs[j];

  float av[8];
#pragma unroll
  for (int j = 0; j < 8; ++j)
    av[j] = gt[(size_t)(s0 + j) * 16 + h] - cs[j];
  float rmax = -1e30f, pm[8];
#pragma unroll
  for (int j = 0; j < 8; ++j) { rmax = fmaxf(rmax, av[j]); pm[j] = rmax; }

  float tm = rmax;
  tm = fmaxf(tm, __shfl_xor(tm, 1));
  tm = fmaxf(tm, __shfl_xor(tm, 2));
  tm = fmaxf(tm, __shfl_xor(tm, 4));
  if ((lane & 7) == 0) Cg[bh * 32 + (tid >> 3)] = tm * kLog2e;

  float4 wtlo, wthi;
  wtlo.x = exp2f((av[0] - tm) * kLog2e); wtlo.y = exp2f((av[1] - tm) * kLog2e);
  wtlo.z = exp2f((av[2] - tm) * kLog2e); wtlo.w = exp2f((av[3] - tm) * kLog2e);
  wthi.x = exp2f((av[4] - tm) * kLog2e); wthi.y = exp2f((av[5] - tm) * kLog2e);
  wthi.z = exp2f((av[6] - tm) * kLog2e); wthi.w = exp2f((av[7] - tm) * kLog2e);

  float mi = rmax;
#pragma unroll
  for (int d = 1; d < 64; d <<= 1) {
    const float t = __shfl_up(mi, d);
    if (lane >= d) mi = fmaxf(mi, t);
  }
  if (lane == 63) wmax[w] = mi;
  float mexcl = __shfl_up(mi, 1);
  if (lane == 0) mexcl = -1e30f;
  __syncthreads();
  float wmoff = -1e30f;
#pragma unroll
  for (int i = 0; i < 4; ++i) if (i < w) wmoff = fmaxf(wmoff, wmax[i]);
  const float mbase = fmaxf(wmoff, mexcl);

  float M[8];
#pragma unroll
  for (int j = 0; j < 8; ++j) M[j] = fmaxf(mbase, pm[j]);
  float4 m2lo, m2hi, nflo, nfhi;
  m2lo.x = M[0] * kLog2e; m2lo.y = M[1] * kLog2e; m2lo.z = M[2] * kLog2e; m2lo.w = M[3] * kLog2e;
  m2hi.x = M[4] * kLog2e; m2hi.y = M[5] * kLog2e; m2hi.z = M[6] * kLog2e; m2hi.w = M[7] * kLog2e;
  nflo.x = expf(-(cs[0] + M[0])); nflo.y = expf(-(cs[1] + M[1]));
  nflo.z = expf(-(cs[2] + M[2])); nflo.w = expf(-(cs[3] + M[3]));
  nfhi.x = expf(-(cs[4] + M[4])); nfhi.y = expf(-(cs[5] + M[5]));
  nfhi.z = expf(-(cs[6] + M[6])); nfhi.w = expf(-(cs[7] + M[7]));
  const size_t o = (size_t)bh * kS + s0;
  *reinterpret_cast<float4*>(wt_out + o) = wtlo;
  *reinterpret_cast<float4*>(wt_out + o + 4) = wthi;
  *reinterpret_cast<float4*>(M2_out + o) = m2lo;
  *reinterpret_cast<float4*>(M2_out + o + 4) = m2hi;
  *reinterpret_cast<float4*>(nfl_out + o) = nflo;
  *reinterpret_cast<float4*>(nfl_out + o + 4) = nfhi;
}

// ---------------- attn: 4 waves, 32x32 MFMA, single-buffer LDS (33 KB -> 4 blocks/CU) ----------------
__global__ __launch_bounds__(256, 2) void attn_mfma_kernel(
    const float* __restrict__ qg, const ushort* __restrict__ Kb,
    const ushort* __restrict__ Vtb, const float* __restrict__ wt,
    const float* __restrict__ Cg, const float* __restrict__ M2,
    const float* __restrict__ nfl, const float* __restrict__ nw,
    float* __restrict__ out, float* __restrict__ ph, float* __restrict__ prs) {
  // XCD-capacity swizzle: each XCD sees only 2 bh -> K/V fits 4MB L2
  const int id = blockIdx.x;
  const int r8 = id & 7, qq = id >> 3;
  const int bh = r8 + 8 * (qq & 1);
  const int u = kOrder[qq >> 1];
  const int b = bh >> 3, h = bh & 7;
  int it, j0, j1, cid = -1;
  if (u <= 6) { it = u; const int T = 2 * it + 2; j0 = 0; j1 = T - 1; }
  else if (u <= 20) {
    const int s = u - 7; it = 7 + (s >> 1); const int ci = s & 1;
    const int T = 2 * it + 2;
    j0 = (T * ci) >> 1; j1 = ((T * (ci + 1)) >> 1) - 1;
    cid = bh * kSplitPerBh + (u - 7);
  } else {
    const int s = u - 21; it = 14 + (s >= 3 ? 1 : 0); const int ci = s - (s >= 3 ? 3 : 0);
    const int T = 2 * it + 2;
    j0 = (T * ci) / 3; j1 = (T * (ci + 1)) / 3 - 1;
    cid = bh * kSplitPerBh + (u - 7);
  }
  const int tid = threadIdx.x;
  const int w = tid >> 6, lane = tid & 63;
  const int l31 = lane & 31, hi = lane >> 5;
  const int row_w = it * 128 + w * 32;
  const int ig = row_w + l31;
  const size_t bhS = (size_t)bh * kS;

  __shared__ ushort Klds[64 * 128];   // 16 KB, single buffer
  __shared__ ushort Vlds[128 * 64];   // 16 KB
  __shared__ float Wtl[64];           // 256 B decay weights

  const char* __restrict__ KgBase = reinterpret_cast<const char*>(Kb + bhS * 128);
  const char* __restrict__ VgBase = reinterpret_cast<const char*>(Vtb + (size_t)bh * 128 * kS);
  const char* __restrict__ WgBase = reinterpret_cast<const char*>(wt + bhS);

  // Q fragments: B[k=d][col=i]
  bf16x8 qf[8];
  {
    const float scale = 0.08838834764831845f;
    const float* qrow = qg + ((size_t)b * kS + ig) * kE + h * kDH;
#pragma unroll
    for (int ks = 0; ks < 8; ++ks) {
      const int d0 = ks * 16 + hi * 8;
      const float4 lo = *reinterpret_cast<const float4*>(qrow + d0);
      const float4 hi4 = *reinterpret_cast<const float4*>(qrow + d0 + 4);
      UB8 f;
      f.u.x = pk2(lo.x * scale, lo.y * scale);
      f.u.y = pk2(lo.z * scale, lo.w * scale);
      f.u.z = pk2(hi4.x * scale, hi4.y * scale);
      f.u.w = pk2(hi4.z * scale, hi4.w * scale);
      qf[ks] = f.f;
    }
  }
  const float M2i = M2[bhS + ig];
  const float cgreg = Cg[bh * 32 + l31];     // all 32 tile maxima in regs

  int koffG[4], voffG[4];
#pragma unroll
  for (int i = 0; i < 4; ++i) {
    const int L = tid * 16 + i * 4096;
    { const int j = L >> 8, c = (L >> 4) & 15;
      koffG[i] = j * 256 + ((c ^ (j & 15)) << 4); }
    { const int d = L >> 7, c = (L >> 4) & 7;
      voffG[i] = d * 4096 + ((c ^ (d & 7)) << 4); }
  }
  auto stage = [&](int jt) {
    const char* Kg = KgBase + (size_t)jt * 16384;
    const char* Vg = VgBase + (size_t)jt * 128;
    char* kl = reinterpret_cast<char*>(Klds) + tid * 16;
    char* vl = reinterpret_cast<char*>(Vlds) + tid * 16;
#pragma unroll
    for (int i = 0; i < 4; ++i) gload16(Kg + koffG[i], kl + i * 4096);
#pragma unroll
    for (int i = 0; i < 4; ++i) gload16(Vg + voffG[i], vl + i * 4096);
    if (tid < 16)
      gload16(WgBase + jt * 256 + tid * 16,
              reinterpret_cast<char*>(Wtl) + tid * 16);
  };

  f32x16 hacc[4];
#pragma unroll
  for (int dc = 0; dc < 4; ++dc) hacc[dc] = zero16();
  float rs = 0.f;

  for (int jt = j0; jt <= j1; ++jt) {
    __syncthreads();            // all waves done reading previous tile
    stage(jt);
    __syncthreads();            // staging loads landed (vmcnt drained at barrier)

    const int jlo = jt * 64;
    const bool v0 = (jlo <= row_w + 31);
    const bool v1 = (jlo + 32 <= row_w + 31);
    const bool fullmask = (jlo + 63 <= row_w);
    if (!v0) continue;

    const float f = exp2f(__shfl(cgreg, jt) - M2i);   // no memory access
    const char* kb = reinterpret_cast<const char*>(Klds);
    const char* vb = reinterpret_cast<const char*>(Vlds);
    const int ksw = (l31 & 15) << 4;

    // ---- swapped QK: S^T[j][i] ----
    f32x16 sacc0 = zero16(), sacc1 = zero16();
#pragma unroll
    for (int ks = 0; ks < 8; ++ks) {
      const int colb = 32 * ks + 16 * hi;
      const bf16x8 kf0 = *reinterpret_cast<const bf16x8*>(
          kb + l31 * 256 + (colb ^ ksw));
      sacc0 = __builtin_amdgcn_mfma_f32_32x32x16_bf16(kf0, qf[ks], sacc0, 0, 0, 0);
      if (v1) {
        const bf16x8 kf1 = *reinterpret_cast<const bf16x8*>(
            kb + (32 + l31) * 256 + (colb ^ ksw));
        sacc1 = __builtin_amdgcn_mfma_f32_32x32x16_bf16(kf1, qf[ks], sacc1, 0, 0, 0);
      }
    }

    // ---- P = S' * wt[j] * f (wt via broadcast b128 from LDS; mask on diagonal) ----
    uint pkw[2][8];
#pragma unroll
    for (int jc = 0; jc < 2; ++jc) {
      if (jc == 1 && !v1) break;
      const f32x16 sa = jc ? sacc1 : sacc0;
      float p[16];
#pragma unroll
      for (int q2 = 0; q2 < 4; ++q2) {
        const float4 wq = *reinterpret_cast<const float4*>(
            &Wtl[jc * 32 + q2 * 8 + 4 * hi]);
        const float wv[4] = {wq.x, wq.y, wq.z, wq.w};
#pragma unroll
        for (int m = 0; m < 4; ++m) {
          const int r = q2 * 4 + m;
          const int c = m + 8 * q2;
          float val = sa[r] * (wv[m] * f);
          if (!fullmask) val = (jlo + jc * 32 + c + 4 * hi <= ig) ? val : 0.f;
          rs += val; p[r] = val;
        }
      }
#pragma unroll
      for (int q2 = 0; q2 < 8; ++q2) pkw[jc][q2] = pk2(p[2 * q2], p[2 * q2 + 1]);
    }

    // ---- PV: H[i][d] ----
#pragma unroll
    for (int ks = 0; ks < 4; ++ks) {
      const int jc = ks >> 1, ks2 = ks & 1;
      if (jc == 1 && !v1) break;
      UB8 pf;
      pf.u.x = pkw[jc][ks2 * 4 + 0]; pf.u.y = pkw[jc][ks2 * 4 + 1];
      pf.u.z = pkw[jc][ks2 * 4 + 2]; pf.u.w = pkw[jc][ks2 * 4 + 3];
      const int colb = 64 * jc + 32 * ks2 + 8 * hi;
#pragma unroll
      for (int dc = 0; dc < 4; ++dc) {
        const int d = dc * 32 + l31;
        const char* vrow = vb + d * 128;
        const int sw = (d & 7) << 4;
        const uint2 a = *reinterpret_cast<const uint2*>(vrow + (colb ^ sw));
        const uint2 c = *reinterpret_cast<const uint2*>(vrow + ((colb + 16) ^ sw));
        UB8 vf; vf.u.x = a.x; vf.u.y = a.y; vf.u.z = c.x; vf.u.w = c.y;
        hacc[dc] = __builtin_amdgcn_mfma_f32_32x32x16_bf16(pf.f, vf.f, hacc[dc], 0, 0, 0);
      }
    }
  }

  const float rs_tot = rs + __shfl_xor(rs, 32);

  if (cid >= 0) {
    float* pb = ph + (size_t)cid * 16384;
#pragma unroll
    for (int dc = 0; dc < 4; ++dc)
#pragma unroll
      for (int r = 0; r < 16; ++r) {
        const int il = w * 32 + (r & 3) + 8 * (r >> 2) + 4 * hi;
        pb[il * 128 + dc * 32 + l31] = hacc[dc][r];
      }
    if (hi == 0) prs[cid * 128 + w * 32 + l31] = rs_tot;
    return;
  }

  // ---- inline epilogue (rowsum via shfl; no LDS) ----
  float nwv[4];
#pragma unroll
  for (int dc = 0; dc < 4; ++dc) nwv[dc] = nw[h * kDH + dc * 32 + l31];
#pragma unroll
  for (int r = 0; r < 16; ++r) {
    const int imap = (r & 3) + 8 * (r >> 2) + 4 * hi;
    const float rsum = __shfl(rs_tot, imap);
    const float nf = nfl[bhS + row_w + imap];
    const float inv = 1.f / (fmaxf(fabsf(rsum), nf) + 1e-6f);
    float hv[4];
    float s1 = 0.f, s2 = 0.f;
#pragma unroll
    for (int dc = 0; dc < 4; ++dc) {
      hv[dc] = hacc[dc][r] * inv;
      s1 += hv[dc]; s2 += hv[dc] * hv[dc];
    }
#pragma unroll
    for (int off = 1; off <= 16; off <<= 1) {
      s1 += __shfl_xor(s1, off);
      s2 += __shfl_xor(s2, off);
    }
    const float mu = s1 * (1.f / 128.f);
    const float var = s2 * (1.f / 128.f) - mu * mu;
    const float rstd = rsqrtf(var + 1e-5f);
    float* __restrict__ orow = out + ((size_t)b * kS + row_w + imap) * kE + h * kDH;
#pragma unroll
    for (int dc = 0; dc < 4; ++dc)
      orow[dc * 32 + l31] = (hv[dc] - mu) * rstd * nwv[dc];
  }
}

// ---------------- combine: sum chunk partials, normalize, groupnorm, store ----------------
__global__ __launch_bounds__(256) void combine_kernel(
    const float* __restrict__ ph, const float* __restrict__ prs,
    const float* __restrict__ nfl, const float* __restrict__ nw,
    float* __restrict__ out) {
  const int blk = blockIdx.x;
  const int bh = blk / 9, ct = blk % 9;
  const int b = bh >> 3, h = bh & 7;
  const int it = 7 + ct;
  const int nc = (ct < 7) ? 2 : 3;
  const int cb0 = bh * kSplitPerBh + ((ct < 7) ? ct * 2 : 14 + (ct - 7) * 3);
  const int tid = threadIdx.x;
  __shared__ float sinv[128];
  if (tid < 128) {
    float rsum = 0.f;
    for (int c = 0; c < nc; ++c) rsum += prs[(cb0 + c) * 128 + tid];
    const float nf = nfl[(size_t)bh * kS + it * 128 + tid];
    sinv[tid] = 1.f / (fmaxf(fabsf(rsum), nf) + 1e-6f);
  }
  __syncthreads();
  for (int kk = 0; kk < 16; ++kk) {
    const int idx = kk * 256 + tid;
    const int row = idx >> 5, c4 = idx & 31;
    float ax = 0.f, ay = 0.f, az = 0.f, aw = 0.f;
    for (int c = 0; c < nc; ++c) {
      const float4 t = *reinterpret_cast<const float4*>(
          ph + (size_t)(cb0 + c) * 16384 + row * 128 + c4 * 4);
      ax += t.x; ay += t.y; az += t.z; aw += t.w;
    }
    const float inv = sinv[row];
    ax *= inv; ay *= inv; az *= inv; aw *= inv;
    float s1 = ax + ay + az + aw;
    float s2 = ax * ax + ay * ay + az * az + aw * aw;
#pragma unroll
    for (int off = 1; off <= 16; off <<= 1) {
      s1 += __shfl_xor(s1, off);
      s2 += __shfl_xor(s2, off);
    }
    const float mu = s1 * (1.f / 128.f);
    const float var = s2 * (1.f / 128.f) - mu * mu;
    const float rstd = rsqrtf(var + 1e-5f);
    const float4 nw4 = *reinterpret_cast<const float4*>(nw + h * kDH + c4 * 4);
    float4 o;
    o.x = (ax - mu) * rstd * nw4.x;
    o.y = (ay - mu) * rstd * nw4.y;
    o.z = (az - mu) * rstd * nw4.z;
    o.w = (aw - mu) * rstd * nw4.w;
    *reinterpret_cast<float4*>(
        out + ((size_t)b * kS + it * 128 + row) * kE + h * kDH + c4 * 4) = o;
  }
}

extern "C" void kernel_launch(void* const* d_in, const int* in_sizes, int n_in,
                              void* d_out, int out_size, void* d_ws, size_t ws_size,
                              hipStream_t stream) {
  const float* q  = (const float*)d_in[0];
  const float* k  = (const float*)d_in[1];
  const float* v  = (const float*)d_in[2];
  const float* iw = (const float*)d_in[3];
  const float* ib = (const float*)d_in[4];
  const float* fw = (const float*)d_in[5];
  const float* fb = (const float*)d_in[6];
  const float* nw = (const float*)d_in[7];
  float* out = (float*)d_out;

  char* ws = (char*)d_ws;
  const int BHS = kB * kNH * kS;                 // 32768
  float* gtmp  = (float*)ws;                     // 4096 tokens x 16 gates = 256 KB
  float* wt    = gtmp + 2 * BHS;
  float* M2    = gtmp + 3 * BHS;
  float* nfl   = gtmp + 4 * BHS;
  float* Cg    = gtmp + 5 * BHS;                 // 512 floats
  ushort* Kb  = (ushort*)(ws + (size_t)(5 * BHS + 512) * 4);
  ushort* Vtb = Kb + (size_t)kB * kNH * kS * kDH;
  float* ph   = (float*)(Vtb + (size_t)kB * kNH * kS * kDH);
  float* prs  = ph + (size_t)320 * 128 * 128;

  prep_kernel<<<dim3(1280), dim3(256), 0, stream>>>(q, k, v, iw, ib, fw, fb,
                                                    Kb, Vtb, gtmp);
  scan_kernel<<<dim3(kB * kNH), dim3(256), 0, stream>>>(gtmp, wt, M2, nfl, Cg);
  attn_mfma_kernel<<<dim3(kUnits * kB * kNH), dim3(256), 0, stream>>>(
      q, Kb, Vtb, wt, Cg, M2, nfl, nw, out, ph, prs);
  combine_kernel<<<dim3(kB * kNH * 9), dim3(256), 0, stream>>>(ph, prs, nfl, nw, out);
}